// Round 7
// baseline (194.682 us; speedup 1.0000x reference)
//
#include <hip/hip_runtime.h>

using frag_t = __attribute__((ext_vector_type(8))) short;   // 8 x bf16 (4 VGPRs)
using f32x4  = __attribute__((ext_vector_type(4))) float;   // MFMA C/D

#define L2E 1.4426950408889634f

constexpr int B_  = 2, S_ = 2048, D_ = 1024, H_ = 16, HD_ = 64;
constexpr int M_  = B_ * S_;      // 4096
constexpr float QSCALE = 0.125f * L2E;   // fold softmax log2e into Q

__device__ __forceinline__ ushort f2bf(float f) {
  union { float f; unsigned u; } v; v.f = f;
  unsigned u = v.u;
  unsigned r = (u + 0x7FFFu + ((u >> 16) & 1u)) >> 16;  // round-nearest-even
  return (ushort)r;
}
__device__ __forceinline__ ushort f2bf_fast(float f) {   // round-half-up, 2 VALU ops
  union { float f; unsigned u; } v; v.f = f;
  return (ushort)((v.u + 0x8000u) >> 16);
}

// async 16B/lane global->LDS (lds dest = wave-uniform base + lane*16) [m97]
__device__ __forceinline__ void gld_lds16(const ushort* g, ushort* l) {
  __builtin_amdgcn_global_load_lds((const __attribute__((address_space(1))) void*)g,
                                   (__attribute__((address_space(3))) void*)l, 16, 0, 0);
}

// ---------- fused prep: x->bf16  |  Wqkv^T->bf16  |  Wproj^T->bf16 ----------
__global__ __launch_bounds__(256) void k_prep(
    const float* __restrict__ x, const float* __restrict__ Wqkv,
    const float* __restrict__ Wproj,
    ushort* __restrict__ Xbf, ushort* __restrict__ Wqt, ushort* __restrict__ Wpt) {
  int blk = blockIdx.x, tid = threadIdx.x;
  if (blk < 1024) {                                 // x convert: 4096 elems/block
    size_t base = (size_t)blk * 4096 + tid * 4;
    #pragma unroll
    for (int i = 0; i < 4; ++i) {
      float4 f = *(const float4*)(x + base + i * 1024);
      ushort4 o;
      o.x = f2bf(f.x); o.y = f2bf(f.y); o.z = f2bf(f.z); o.w = f2bf(f.w);
      *(ushort4*)(Xbf + base + i * 1024) = o;
    }
  } else {                                          // W [K,N] -> W^T [N,K] bf16, 64x64 tile
    __shared__ float tile[64][65];
    const float* in; ushort* out; int N, K, bx, by;
    if (blk < 1024 + 768) { int b2 = blk - 1024; in = Wqkv;  out = Wqt; N = 3072; K = 1024; bx = b2 % 48; by = b2 / 48; }
    else                  { int b2 = blk - 1792; in = Wproj; out = Wpt; N = 1024; K = 1024; bx = b2 % 16; by = b2 / 16; }
    int n0 = bx * 64, k0 = by * 64;
    int tx = tid & 63, ty = tid >> 6;               // (64,4)
    #pragma unroll
    for (int i = 0; i < 16; ++i)
      tile[ty + i * 4][tx] = in[(size_t)(k0 + ty + i * 4) * N + n0 + tx];
    __syncthreads();
    #pragma unroll
    for (int i = 0; i < 16; ++i)
      out[(size_t)(n0 + ty + i * 4) * K + k0 + tx] = f2bf(tile[tx][ty + i * 4]);
  }
}

// ---------- bf16 MFMA GEMM: C[M,N] = A[M,K] @ Bt[N,K]^T + bias ----------
// AITER-style pipelined K-loop: 3-stage LDS buffers (BK=32), async
// global_load_lds prefetch of tile k+2 during compute of tile k, and a
// fine-grained s_waitcnt vmcnt(NDMA) + raw s_barrier at iter top — the
// newest stage stays IN FLIGHT across the barrier (never vmcnt(0); the
// m97 2-barrier structure's drain was the ~60% stall here).
// 3-buffer rotation => one barrier/iter is sufficient: stage(k+2) writes
// buf((k+2)%3)=buf((k-1)%3), whose readers (comp(k-1)) all passed barrier k.
// BK=32 swizzle: global chunk (lane&3)^((lane>>2)&3)^((lane>>4)&3); read
// slot quad^((li^(li>>2))&3) -> 2 lanes/bank-group (free, m136).
// EPI 0: BM=128; Q(*0.125*log2e)/K head layouts; V via per-wave LDS
//        transpose -> V^T coalesced.  EPI 1: BM=64 (grid 512 = 2 WG/CU), f32 out.
template <int EPI>
__global__ __launch_bounds__(256) void k_gemm(
    const ushort* __restrict__ A, const ushort* __restrict__ Bt,
    const float* __restrict__ bias,
    ushort* __restrict__ Qo, ushort* __restrict__ Ko, ushort* __restrict__ Vo,
    float* __restrict__ Co, int N, int K) {
  constexpr int BM = (EPI == 0) ? 128 : 64;
  constexpr int BN = 128, BK = 32;
  constexpr int MI = 4, NI = (EPI == 0) ? 4 : 2;
  constexpr int NDMA = (EPI == 0) ? 4 : 3;          // DMA insts per wave per stage
  __shared__ ushort As[3][BM * BK];
  __shared__ ushort Bs[3][BN * BK];
  int tid  = threadIdx.x;
  int lane = tid & 63, wave = tid >> 6;
  int quad = lane >> 4, li = lane & 15;
  int m0 = blockIdx.y * BM, n0 = blockIdx.x * BN;
  int srow   = lane >> 2;                           // 16 rows per DMA inst
  int gchunk = (lane & 3) ^ (srow & 3) ^ ((lane >> 4) & 3);  // swizzled 16B chunk
  int rsl    = (li ^ (li >> 2)) & 3;                // read-side XOR
  int mbase  = (EPI == 0) ? (wave >> 1) * 64 : 0;
  int nbase  = (EPI == 0) ? (wave & 1) * 64 : wave * 32;
  int niter  = K / BK;

  auto stage = [&](int it, int b) {
    int k0 = it * BK;
    if (EPI == 0) {
      #pragma unroll
      for (int i = 0; i < 2; ++i) {
        int rbase = wave * 32 + i * 16;
        gld_lds16(&A [(size_t)(m0 + rbase + srow) * K + k0 + gchunk * 8], &As[b][rbase * BK]);
        gld_lds16(&Bt[(size_t)(n0 + rbase + srow) * K + k0 + gchunk * 8], &Bs[b][rbase * BK]);
      }
    } else {
      int ra = wave * 16;
      gld_lds16(&A[(size_t)(m0 + ra + srow) * K + k0 + gchunk * 8], &As[b][ra * BK]);
      #pragma unroll
      for (int i = 0; i < 2; ++i) {
        int rbase = wave * 32 + i * 16;
        gld_lds16(&Bt[(size_t)(n0 + rbase + srow) * K + k0 + gchunk * 8], &Bs[b][rbase * BK]);
      }
    }
  };

  f32x4 acc[MI][NI] = {};
  stage(0, 0);
  stage(1, 1);
  for (int it = 0; it < niter; ++it) {
    __builtin_amdgcn_s_waitcnt(0x0F70 | NDMA);      // own stage(it) landed; stage(it+1) stays in flight
    __builtin_amdgcn_s_barrier();                   // all waves' stage(it) landed; all passed comp(it-1)
    __builtin_amdgcn_sched_barrier(0);              // pin: no ds_read hoists above the sync point
    int ipre = (it + 2 < niter) ? it + 2 : niter - 1;  // tail: redundant re-stage keeps vmcnt cadence
    stage(ipre, (it + 2) % 3);
    int b = it % 3;
    frag_t af[MI], bf[NI];
    #pragma unroll
    for (int mi = 0; mi < MI; ++mi)
      af[mi] = *(const frag_t*)&As[b][(mbase + mi * 16 + li) * BK + ((quad ^ rsl) * 8)];
    #pragma unroll
    for (int ni = 0; ni < NI; ++ni)
      bf[ni] = *(const frag_t*)&Bs[b][(nbase + ni * 16 + li) * BK + ((quad ^ rsl) * 8)];
    #pragma unroll
    for (int mi = 0; mi < MI; ++mi)
      #pragma unroll
      for (int ni = 0; ni < NI; ++ni)
        acc[mi][ni] = __builtin_amdgcn_mfma_f32_16x16x32_bf16(af[mi], bf[ni], acc[mi][ni], 0, 0, 0);
  }
  __syncthreads();                                  // full drain before LDS reuse / exit

  // epilogue: C/D layout row = quad*4+reg, col = li  [measured m89/m91]
  if (EPI == 1) {
    #pragma unroll
    for (int mi = 0; mi < MI; ++mi)
      #pragma unroll
      for (int ni = 0; ni < NI; ++ni) {
        int gcol = n0 + nbase + ni * 16 + li;
        float bv = bias[gcol];
        #pragma unroll
        for (int r = 0; r < 4; ++r) {
          int grow = m0 + mbase + mi * 16 + quad * 4 + r;
          Co[(size_t)grow * N + gcol] = acc[mi][ni][r] + bv;
        }
      }
  } else {
    int which = (n0 + nbase) >> 10;                 // wave-uniform (64-aligned quarters)
    if (which < 2) {                                // Q / K: [bh][s][hd]
      #pragma unroll
      for (int mi = 0; mi < MI; ++mi)
        #pragma unroll
        for (int ni = 0; ni < NI; ++ni) {
          int gcol = n0 + nbase + ni * 16 + li;
          float bv = bias[gcol];
          #pragma unroll
          for (int r = 0; r < 4; ++r) {
            int grow = m0 + mbase + mi * 16 + quad * 4 + r;
            float v = acc[mi][ni][r] + bv;
            int d = gcol & 1023, h = d >> 6, hd = d & 63;
            int b = grow >> 11, s = grow & 2047;
            size_t bh = (size_t)b * H_ + h;
            if (which == 0) Qo[(bh * S_ + s) * HD_ + hd] = f2bf(v * QSCALE);
            else            Ko[(bh * S_ + s) * HD_ + hd] = f2bf(v);
          }
        }
    } else {                                        // V: per-wave LDS transpose -> coalesced V^T
      ushort* vlds = ((ushort*)As) + wave * (64 * 72);  // staging LDS dead after drain
      #pragma unroll
      for (int ni = 0; ni < NI; ++ni) {
        float bv = bias[n0 + nbase + ni * 16 + li];
        #pragma unroll
        for (int mi = 0; mi < MI; ++mi)
          #pragma unroll
          for (int r = 0; r < 4; ++r)
            vlds[(ni * 16 + li) * 72 + mi * 16 + quad * 4 + r] = f2bf(acc[mi][ni][r] + bv);
      }                                             // wave-private: in-order ds, no barrier
      int hgrp = ((n0 & 1023) + nbase) >> 6;
      int b = m0 >> 11;
      int s0 = (m0 & 2047) + mbase;
      size_t vbase = (size_t)(b * H_ + hgrp) * HD_ * S_;
      #pragma unroll
      for (int i = 0; i < 8; ++i) {
        int row = i * 8 + (lane >> 3);              // hd
        int col = (lane & 7) * 8;                   // s offset, 16B aligned
        *(uint4*)&Vo[vbase + (size_t)row * S_ + s0 + col] = *(const uint4*)&vlds[row * 72 + col];
      }
    }
  }
}

// ---------- causal flash attention (unchanged from R6) ----------
__global__ __launch_bounds__(256) void k_attn(
    const ushort* __restrict__ Q, const ushort* __restrict__ K,
    const ushort* __restrict__ Vt, ushort* __restrict__ O) {
  __shared__ ushort Kbuf[2][64 * 64];
  __shared__ ushort Vbuf[2][64 * 64];
  __shared__ ushort Plds[4 * 16 * 64];             // per-wave P buffer (C->A transform)
  int lane = threadIdx.x & 63, wave = threadIdx.x >> 6;
  int quad = lane >> 4, li = lane & 15;
  int bh = blockIdx.x;                             // x = bh: XCD round-robin, K/V hot in L2
  int qb = 31 - (int)blockIdx.y;                   // heavy q-tiles dispatch first
  int b = bh >> 4, h = bh & 15;
  int q0 = qb * 64 + wave * 16;
  const ushort* Qb = Q  + (size_t)bh * S_ * HD_;
  const ushort* Kb = K  + (size_t)bh * S_ * HD_;
  const ushort* Vb = Vt + (size_t)bh * HD_ * S_;
  ushort* Pw = &Plds[wave * 1024];

  frag_t qf[2];  // A-operand: m = li, k = quad*8+j  [measured m120]
  #pragma unroll
  for (int ks = 0; ks < 2; ++ks)
    qf[ks] = *(const frag_t*)&Qb[(size_t)(q0 + li) * HD_ + ks * 32 + quad * 8];

  f32x4 o[4] = {};
  float l_r[4] = {0.f, 0.f, 0.f, 0.f};

  auto stage = [&](int kb, int bi) {
    #pragma unroll
    for (int i = 0; i < 2; ++i) {
      int rt  = wave * 16 + i * 8 + (lane >> 3);   // tile row
      int c16 = (lane & 7) ^ (lane >> 3);          // swizzle: (rt&7) == lane>>3
      gld_lds16(&Kb[(size_t)(kb * 64 + rt) * HD_ + c16 * 8], &Kbuf[bi][(wave * 16 + i * 8) * 64]);
      gld_lds16(&Vb[(size_t)rt * S_ + kb * 64 + c16 * 8],    &Vbuf[bi][(wave * 16 + i * 8) * 64]);
    }
  };

  auto comp = [&](int kb, bool diag, int bi) {
    f32x4 sc[4];
    #pragma unroll
    for (int t = 0; t < 4; ++t) {
      f32x4 a = {};
      #pragma unroll
      for (int ks = 0; ks < 2; ++ks) {
        frag_t kf = *(const frag_t*)&Kbuf[bi][(t * 16 + li) * 64 + (((quad + ks * 4) ^ (li & 7)) * 8)];
        a = __builtin_amdgcn_mfma_f32_16x16x32_bf16(qf[ks], kf, a, 0, 0, 0);
      }
      sc[t] = a;
    }
    if (diag) {
      #pragma unroll
      for (int t = 0; t < 4; ++t) {
        int key = kb * 64 + t * 16 + li;
        #pragma unroll
        for (int r = 0; r < 4; ++r)
          if (key > q0 + quad * 4 + r) sc[t][r] = -1e30f;
      }
    }
    #pragma unroll
    for (int t = 0; t < 4; ++t)
      #pragma unroll
      for (int r = 0; r < 4; ++r) {
        float p = exp2f(sc[t][r]);                 // log2e folded into Q; masked -> 0
        l_r[r] += p;
        int row = quad * 4 + r;
        int swr = ((row >> 2) << 1) | (row & 1);
        Pw[row * 64 + (((t * 2 + (li >> 3)) ^ swr) * 8) + (li & 7)] = f2bf_fast(p);
      }
    frag_t pf[2];                                  // wave-private LDS: in-order, no barrier
    int swl = ((li >> 2) << 1) | (li & 1);
    #pragma unroll
    for (int ks = 0; ks < 2; ++ks)
      pf[ks] = *(const frag_t*)&Pw[li * 64 + (((ks * 4 + quad) ^ swl) * 8)];
    #pragma unroll
    for (int t = 0; t < 4; ++t)
      #pragma unroll
      for (int ks = 0; ks < 2; ++ks) {
        frag_t vf = *(const frag_t*)&Vbuf[bi][(t * 16 + li) * 64 + (((quad + ks * 4) ^ (li & 7)) * 8)];
        o[t] = __builtin_amdgcn_mfma_f32_16x16x32_bf16(pf[ks], vf, o[t], 0, 0, 0);
      }
  };

  stage(0, 0);
  __syncthreads();                                 // DMA for kb=0 landed
  for (int kb = 0; kb <= qb; ++kb) {
    if (kb < qb) stage(kb + 1, (kb + 1) & 1);      // async DMA overlaps comp below
    comp(kb, kb == qb, kb & 1);
    __syncthreads();                               // drains DMA + guards buffer reuse
  }

  #pragma unroll
  for (int r = 0; r < 4; ++r) {
    float t = l_r[r];                              // one reduce per tile
    #pragma unroll
    for (int off = 1; off < 16; off <<= 1) t += __shfl_xor(t, off);
    float inv = 1.f / t;
    int srow = q0 + quad * 4 + r;
    #pragma unroll
    for (int ht = 0; ht < 4; ++ht)
      O[((size_t)b * S_ + srow) * D_ + h * 64 + ht * 16 + li] = f2bf(o[ht][r] * inv);
  }
}

extern "C" void kernel_launch(void* const* d_in, const int* in_sizes, int n_in,
                              void* d_out, int out_size, void* d_ws, size_t ws_size,
                              hipStream_t stream) {
  (void)in_sizes; (void)n_in; (void)out_size; (void)ws_size;
  const float* x     = (const float*)d_in[0];
  const float* Wqkv  = (const float*)d_in[1];
  const float* bqkv  = (const float*)d_in[2];
  const float* Wproj = (const float*)d_in[3];
  const float* bproj = (const float*)d_in[4];
  float* out = (float*)d_out;

  char* ws = (char*)d_ws;                          // 40 MB used
  ushort* Xbf = (ushort*)(ws);                     //  8 MB  [4096,1024] bf16 (reused as O after attn)
  ushort* Wqt = (ushort*)(ws + (8u  << 20));       //  6 MB  [3072,1024] bf16
  ushort* Wpt = (ushort*)(ws + (14u << 20));       //  2 MB  [1024,1024] bf16
  ushort* Qbf = (ushort*)(ws + (16u << 20));       //  8 MB  [32,2048,64]  (pre-scaled by 0.125*log2e)
  ushort* Kbf = (ushort*)(ws + (24u << 20));       //  8 MB  [32,2048,64]
  ushort* Vtb = (ushort*)(ws + (32u << 20));       //  8 MB  [32,64,2048]  (transposed)
  ushort* Obf = Xbf;                               // X dead after QKV GEMM

  k_prep<<<dim3(2048), dim3(256), 0, stream>>>(x, Wqkv, Wproj, Xbf, Wqt, Wpt);
  k_gemm<0><<<dim3(24, 32), dim3(256), 0, stream>>>(Xbf, Wqt, bqkv, Qbf, Kbf, Vtb,
                                                    (float*)nullptr, 3 * D_, D_);
  k_attn<<<dim3(B_ * H_, 32), dim3(256), 0, stream>>>(Qbf, Kbf, Vtb, Obf);
  k_gemm<1><<<dim3(8, 64), dim3(256), 0, stream>>>(Obf, Wpt, bproj,
                                                   (ushort*)nullptr, (ushort*)nullptr, (ushort*)nullptr,
                                                   out, D_, D_);
}